// Round 1
// baseline (705.889 us; speedup 1.0000x reference)
//
#include <hip/hip_runtime.h>

#define D 128          // D_IN == D_OUT
#define K2 256         // 2*D (concat width)
#define NT 64          // nodes per block
#define NTHREADS 256

__global__ __launch_bounds__(NTHREADS, 2)
void sage_fused_kernel(const float* __restrict__ x,
                       const int* __restrict__ rp,
                       const int* __restrict__ ci,
                       const float* __restrict__ W,
                       const float* __restrict__ lb,
                       const float* __restrict__ bb,
                       float* __restrict__ y,
                       int n_out)
{
    __shared__ float agg[NT][K2 + 2];   // [self(128) | mean(128)], padded stride
    __shared__ float wt[16][D];         // transposed W k-chunk: wt[kk][o]

    const int tid  = threadIdx.x;
    const int wave = tid >> 6;
    const int lane = tid & 63;
    const int node0 = blockIdx.x * NT;

    // ---------- Phase 1: build [self | mean-of-neighbors] rows in LDS ----------
    // Each wave handles 16 nodes; 64 lanes * float2 = one full 512B row per load.
    for (int nn = wave; nn < NT; nn += 4) {
        const int node = node0 + nn;
        if (node >= n_out) continue;
        const float2 self =
            *reinterpret_cast<const float2*>(&x[(size_t)node * D + lane * 2]);
        agg[nn][lane * 2 + 0] = self.x;
        agg[nn][lane * 2 + 1] = self.y;

        const int s = rp[node];
        const int e = rp[node + 1];
        float ax = 0.f, ay = 0.f;
        for (int t = s; t < e; ++t) {
            const int c = ci[t];
            const float2 v =
                *reinterpret_cast<const float2*>(&x[(size_t)c * D + lane * 2]);
            ax += v.x;
            ay += v.y;
        }
        const float inv = 1.0f / (float)max(e - s, 1);
        agg[nn][D + lane * 2 + 0] = ax * inv;
        agg[nn][D + lane * 2 + 1] = ay * inv;
    }

    // ---------- Phase 2: y[tile] = agg @ W^T + lin_bias + bias ----------
    // Thread tile: 8 nodes x 4 outputs. o_grp in [0,32), n_grp in [0,8).
    const int o_grp = tid & 31;
    const int n_grp = tid >> 5;

    float acc[8][4];
    #pragma unroll
    for (int j = 0; j < 8; ++j)
        #pragma unroll
        for (int i = 0; i < 4; ++i) acc[j][i] = 0.f;

    for (int k0 = 0; k0 < K2; k0 += 16) {
        // Stage wt[kk][o] = W[o][k0+kk]  (2048 elems, 8 per thread)
        for (int i = tid; i < 16 * D; i += NTHREADS) {
            const int kk = i >> 7;
            const int o  = i & (D - 1);
            wt[kk][o] = W[o * K2 + k0 + kk];
        }
        __syncthreads();   // wt ready; also orders phase-1 agg writes before reads

        #pragma unroll
        for (int kk = 0; kk < 16; ++kk) {
            const float4 wv =
                *reinterpret_cast<const float4*>(&wt[kk][o_grp * 4]);
            #pragma unroll
            for (int j = 0; j < 8; ++j) {
                const float a = agg[n_grp * 8 + j][k0 + kk];  // half-wave broadcast
                acc[j][0] += a * wv.x;
                acc[j][1] += a * wv.y;
                acc[j][2] += a * wv.z;
                acc[j][3] += a * wv.w;
            }
        }
        __syncthreads();   // protect wt before next chunk overwrites it
    }

    // ---------- Epilogue: add biases, coalesced float4 stores ----------
    const int o = o_grp * 4;
    float4 b4;
    b4.x = lb[o + 0] + bb[o + 0];
    b4.y = lb[o + 1] + bb[o + 1];
    b4.z = lb[o + 2] + bb[o + 2];
    b4.w = lb[o + 3] + bb[o + 3];

    #pragma unroll
    for (int j = 0; j < 8; ++j) {
        const int node = node0 + n_grp * 8 + j;
        if (node < n_out) {
            float4 r;
            r.x = acc[j][0] + b4.x;
            r.y = acc[j][1] + b4.y;
            r.z = acc[j][2] + b4.z;
            r.w = acc[j][3] + b4.w;
            *reinterpret_cast<float4*>(&y[(size_t)node * D + o]) = r;
        }
    }
}

extern "C" void kernel_launch(void* const* d_in, const int* in_sizes, int n_in,
                              void* d_out, int out_size, void* d_ws, size_t ws_size,
                              hipStream_t stream)
{
    const float* x  = (const float*)d_in[0];
    const int*   rp = (const int*)d_in[1];
    const int*   ci = (const int*)d_in[2];
    // d_in[3] = sample_count (scalar) — unused, degree comes from row_ptr
    const float* W  = (const float*)d_in[4];
    const float* lb = (const float*)d_in[5];
    const float* bb = (const float*)d_in[6];
    float* y = (float*)d_out;

    const int n_out = in_sizes[1] - 1;
    const int grid  = (n_out + NT - 1) / NT;

    hipLaunchKernelGGL(sage_fused_kernel, dim3(grid), dim3(NTHREADS), 0, stream,
                       x, rp, ci, W, lb, bb, y, n_out);
}

// Round 2
// 240.391 us; speedup vs baseline: 2.9364x; 2.9364x over previous
//
#include <hip/hip_runtime.h>

#define D 128          // D_IN == D_OUT
#define K2 256         // 2*D (concat width)
#define NT 64          // nodes per block
#define NTHREADS 256
#define AGG_LD 258     // agg row stride (floats), even for float2 alignment
#define WT_LD 132      // wt row stride: 16B-aligned rows, conflict-free-ish writes

__global__ __launch_bounds__(NTHREADS, 2)
void sage_fused2(const float* __restrict__ x,
                 const int* __restrict__ rp,
                 const int* __restrict__ ci,
                 const float* __restrict__ W,
                 const float* __restrict__ lb,
                 const float* __restrict__ bb,
                 float* __restrict__ y,
                 int n_out)
{
    __shared__ float agg[NT][AGG_LD];    // [self(128) | mean(128)]
    __shared__ float wt[16][WT_LD];      // wt[kk][o] = W[o][k0+kk]
    __shared__ int   rpls[NT + 1];
    __shared__ int   cils[NT * 16];

    const int tid   = threadIdx.x;
    const int wave  = tid >> 6;
    const int lane  = tid & 63;
    const int node0 = blockIdx.x * NT;
    const int nt_act = min(NT, n_out - node0);

    // ---- Stage row_ptr slice (broadcast-cheap) ----
    if (tid <= nt_act) rpls[tid] = rp[node0 + tid];
    __syncthreads();

    const int e_base = rpls[0];
    const int e_cnt  = rpls[nt_act] - e_base;
    const bool fits  = (e_cnt <= NT * 16);

    // ---- Stage edge indices into LDS (coalesced) ----
    if (fits) {
        for (int i = tid; i < e_cnt; i += NTHREADS)
            cils[i] = ci[e_base + i];
    }
    __syncthreads();

    // ---- Phase 1: gather. One wave per 16 nodes; 64 lanes x float2 = full row.
    //      deg==16 fast path: 16 INDEPENDENT row loads in flight per node. ----
    for (int t = 0; t < 16; ++t) {
        const int nn = wave * 16 + t;            // wave-uniform
        if (nn >= nt_act) break;
        const int node = node0 + nn;

        const float2 self =
            *reinterpret_cast<const float2*>(&x[(size_t)node * D + lane * 2]);

        const int s = rpls[nn] - e_base;
        const int d = rpls[nn + 1] - e_base - s;

        float ax = 0.f, ay = 0.f;
        if (fits && d == 16) {
            int idx[16];
            #pragma unroll
            for (int u = 0; u < 16; ++u) idx[u] = cils[s + u];
            #pragma unroll
            for (int u = 0; u < 16; ++u) {
                const float2 v = *reinterpret_cast<const float2*>(
                    &x[(size_t)idx[u] * D + lane * 2]);
                ax += v.x;
                ay += v.y;
            }
        } else {
            for (int u = 0; u < d; ++u) {
                const int c = fits ? cils[s + u] : ci[e_base + s + u];
                const float2 v = *reinterpret_cast<const float2*>(
                    &x[(size_t)c * D + lane * 2]);
                ax += v.x;
                ay += v.y;
            }
        }
        const float inv = 1.0f / (float)max(d, 1);
        agg[nn][lane * 2 + 0] = self.x;
        agg[nn][lane * 2 + 1] = self.y;
        agg[nn][D + lane * 2 + 0] = ax * inv;
        agg[nn][D + lane * 2 + 1] = ay * inv;
    }
    // (first GEMM-chunk __syncthreads covers agg visibility)

    // ---- Phase 2: y = agg @ W^T. Thread tile: 8 nodes x 4 outputs. ----
    const int o_grp = tid & 31;   // output group: o = o_grp*4
    const int n_grp = tid >> 5;   // node group: rows n_grp*8 .. +7

    float acc[8][4];
    #pragma unroll
    for (int j = 0; j < 8; ++j)
        #pragma unroll
        for (int i = 0; i < 4; ++i) acc[j][i] = 0.f;

    for (int k0 = 0; k0 < K2; k0 += 16) {
        // Stage wt[kk][o] = W[o][k0+kk]; coalesced float4 global reads,
        // transposed scalar LDS writes (<=2-way alias with WT_LD=132).
        for (int i = tid; i < 512; i += NTHREADS) {   // 512 float4s
            const int row = i >> 2;                   // 0..127 (o)
            const int kq  = i & 3;                    // 0..3
            const float4 w = *reinterpret_cast<const float4*>(
                &W[row * K2 + k0 + kq * 4]);
            wt[kq * 4 + 0][row] = w.x;
            wt[kq * 4 + 1][row] = w.y;
            wt[kq * 4 + 2][row] = w.z;
            wt[kq * 4 + 3][row] = w.w;
        }
        __syncthreads();

        #pragma unroll
        for (int kk2 = 0; kk2 < 8; ++kk2) {           // 2 k per iter
            const float4 w0 = *reinterpret_cast<const float4*>(
                &wt[kk2 * 2 + 0][o_grp * 4]);
            const float4 w1 = *reinterpret_cast<const float4*>(
                &wt[kk2 * 2 + 1][o_grp * 4]);
            #pragma unroll
            for (int j = 0; j < 8; ++j) {
                const float2 a = *reinterpret_cast<const float2*>(
                    &agg[n_grp * 8 + j][k0 + kk2 * 2]);  // half-wave broadcast
                acc[j][0] += a.x * w0.x + a.y * w1.x;
                acc[j][1] += a.x * w0.y + a.y * w1.y;
                acc[j][2] += a.x * w0.z + a.y * w1.z;
                acc[j][3] += a.x * w0.w + a.y * w1.w;
            }
        }
        __syncthreads();
    }

    // ---- Epilogue ----
    const int o = o_grp * 4;
    float4 b4;
    b4.x = lb[o + 0] + bb[o + 0];
    b4.y = lb[o + 1] + bb[o + 1];
    b4.z = lb[o + 2] + bb[o + 2];
    b4.w = lb[o + 3] + bb[o + 3];

    #pragma unroll
    for (int j = 0; j < 8; ++j) {
        const int node = node0 + n_grp * 8 + j;
        if (node < n_out) {
            float4 r;
            r.x = acc[j][0] + b4.x;
            r.y = acc[j][1] + b4.y;
            r.z = acc[j][2] + b4.z;
            r.w = acc[j][3] + b4.w;
            *reinterpret_cast<float4*>(&y[(size_t)node * D + o]) = r;
        }
    }
}

extern "C" void kernel_launch(void* const* d_in, const int* in_sizes, int n_in,
                              void* d_out, int out_size, void* d_ws, size_t ws_size,
                              hipStream_t stream)
{
    const float* x  = (const float*)d_in[0];
    const int*   rp = (const int*)d_in[1];
    const int*   ci = (const int*)d_in[2];
    // d_in[3] = sample_count (scalar) — degree comes from row_ptr
    const float* W  = (const float*)d_in[4];
    const float* lb = (const float*)d_in[5];
    const float* bb = (const float*)d_in[6];
    float* y = (float*)d_out;

    const int n_out = in_sizes[1] - 1;
    const int grid  = (n_out + NT - 1) / NT;

    hipLaunchKernelGGL(sage_fused2, dim3(grid), dim3(NTHREADS), 0, stream,
                       x, rp, ci, W, lb, bb, y, n_out);
}

// Round 3
// 143.774 us; speedup vs baseline: 4.9097x; 1.6720x over previous
//
#include <hip/hip_runtime.h>
#include <hip/hip_bf16.h>

#define D 128          // D_IN == D_OUT
#define K2 256         // 2*D (concat width)
#define NT 64          // nodes per block
#define NTHREADS 256
#define AGG_LD 264     // bf16 elems per aggB row -> 528B stride (16B-aligned, bank-uniform frag reads)

typedef __attribute__((ext_vector_type(8))) short bf16x8;  // MFMA A/B frag (4 VGPRs)
typedef __attribute__((ext_vector_type(4))) float f32x4;   // MFMA C/D frag

static __device__ __forceinline__ unsigned short f2bf(float f) {
    __hip_bfloat16 h = __float2bfloat16(f);   // RNE
    return *reinterpret_cast<unsigned short*>(&h);
}

__global__ __launch_bounds__(NTHREADS, 3)
void sage_fused3(const float* __restrict__ x,
                 const int* __restrict__ rp,
                 const int* __restrict__ ci,
                 const float* __restrict__ W,
                 const float* __restrict__ lb,
                 const float* __restrict__ bb,
                 float* __restrict__ y,
                 int n_out)
{
    __shared__ unsigned short aggB[NT][AGG_LD];  // bf16 [self(128) | mean(128)]
    __shared__ unsigned short wtT[D][32];        // bf16 wtT[o][kk] = W[o][k0+kk], 64B rows
    __shared__ int rpls[NT + 1];
    __shared__ int cils[NT * 16];

    const int tid   = threadIdx.x;
    const int wave  = tid >> 6;
    const int lane  = tid & 63;
    const int node0 = blockIdx.x * NT;
    const int nt_act = min(NT, n_out - node0);

    // ---- Stage row_ptr slice + edge indices (coalesced) ----
    if (tid <= nt_act) rpls[tid] = rp[node0 + tid];
    __syncthreads();
    const int e_base = rpls[0];
    const int e_cnt  = rpls[nt_act] - e_base;
    const bool fits  = (e_cnt <= NT * 16);
    if (fits) {
        for (int i = tid; i < e_cnt; i += NTHREADS) cils[i] = ci[e_base + i];
    }
    __syncthreads();

    // ---- Phase 1: gather (fp32 accumulate, bf16 store to LDS) ----
    // One wave per 16 nodes; 64 lanes x float2 = one full 512B row per load;
    // deg==16 fast path keeps 16 independent row loads in flight.
    for (int t = 0; t < 16; ++t) {
        const int nn = wave * 16 + t;            // wave-uniform
        if (nn >= nt_act) break;
        const int node = node0 + nn;

        const float2 self =
            *reinterpret_cast<const float2*>(&x[(size_t)node * D + lane * 2]);

        const int s  = rpls[nn] - e_base;
        const int dg = rpls[nn + 1] - e_base - s;

        float ax = 0.f, ay = 0.f;
        if (fits && dg == 16) {
            int idx[16];
            #pragma unroll
            for (int u = 0; u < 16; ++u) idx[u] = cils[s + u];
            #pragma unroll
            for (int u = 0; u < 16; ++u) {
                const float2 v = *reinterpret_cast<const float2*>(
                    &x[(size_t)idx[u] * D + lane * 2]);
                ax += v.x; ay += v.y;
            }
        } else {
            for (int u = 0; u < dg; ++u) {
                const int c = fits ? cils[s + u] : ci[e_base + s + u];
                const float2 v = *reinterpret_cast<const float2*>(
                    &x[(size_t)c * D + lane * 2]);
                ax += v.x; ay += v.y;
            }
        }
        const float inv = 1.0f / (float)max(dg, 1);
        const unsigned int ps = (unsigned int)f2bf(self.x)
                              | ((unsigned int)f2bf(self.y) << 16);
        const unsigned int pm = (unsigned int)f2bf(ax * inv)
                              | ((unsigned int)f2bf(ay * inv) << 16);
        *reinterpret_cast<unsigned int*>(&aggB[nn][lane * 2])     = ps;
        *reinterpret_cast<unsigned int*>(&aggB[nn][D + lane * 2]) = pm;
    }
    // (first __syncthreads in GEMM loop publishes aggB)

    // ---- Phase 2: MFMA GEMM. Per wave: M=16 nodes x N=128 outs, K=256 ----
    const int n15 = lane & 15;
    const int g   = lane >> 4;

    f32x4 acc[8];
    #pragma unroll
    for (int f = 0; f < 8; ++f) acc[f] = (f32x4){0.f, 0.f, 0.f, 0.f};

    for (int k0 = 0; k0 < K2; k0 += 32) {
        // Stage wtT[o][kk] = bf16(W[o][k0+kk]); coalesced float4 global reads.
        #pragma unroll
        for (int j = 0; j < 4; ++j) {
            const int idx = j * 256 + tid;       // 1024 float4s per chunk
            const int o   = idx >> 3;            // 0..127
            const int c   = idx & 7;             // 0..7
            const float4 w = *reinterpret_cast<const float4*>(
                &W[(size_t)o * K2 + k0 + c * 4]);
            const unsigned int lo = (unsigned int)f2bf(w.x) | ((unsigned int)f2bf(w.y) << 16);
            const unsigned int hi = (unsigned int)f2bf(w.z) | ((unsigned int)f2bf(w.w) << 16);
            *reinterpret_cast<uint2*>(&wtT[o][c * 4]) = make_uint2(lo, hi);
        }
        __syncthreads();

        // A frag: row = wave*16 + n15, k = k0 + g*8 + j  (16B ds_read, bank-uniform)
        const bf16x8 a = *reinterpret_cast<const bf16x8*>(
            &aggB[wave * 16 + n15][k0 + g * 8]);
        #pragma unroll
        for (int f = 0; f < 8; ++f) {
            // B frag: B[k][n] = W[n][k]; row = f*16 + n15, k-slice = g*8..g*8+7
            const bf16x8 b = *reinterpret_cast<const bf16x8*>(&wtT[f * 16 + n15][g * 8]);
            acc[f] = __builtin_amdgcn_mfma_f32_16x16x32_bf16(a, b, acc[f], 0, 0, 0);
        }
        __syncthreads();   // protect wtT before next chunk overwrite
    }

    // ---- Epilogue: D layout col = lane&15, row = (lane>>4)*4 + reg ----
    const int mbase = node0 + wave * 16 + g * 4;
    #pragma unroll
    for (int f = 0; f < 8; ++f) {
        const int col  = f * 16 + n15;
        const float bs = lb[col] + bb[col];
        #pragma unroll
        for (int r = 0; r < 4; ++r) {
            const int row = mbase + r;
            if (row < n_out)
                y[(size_t)row * D + col] = acc[f][r] + bs;
        }
    }
}

extern "C" void kernel_launch(void* const* d_in, const int* in_sizes, int n_in,
                              void* d_out, int out_size, void* d_ws, size_t ws_size,
                              hipStream_t stream)
{
    const float* x  = (const float*)d_in[0];
    const int*   rp = (const int*)d_in[1];
    const int*   ci = (const int*)d_in[2];
    // d_in[3] = sample_count (scalar) — degree comes from row_ptr
    const float* W  = (const float*)d_in[4];
    const float* lb = (const float*)d_in[5];
    const float* bb = (const float*)d_in[6];
    float* y = (float*)d_out;

    const int n_out = in_sizes[1] - 1;
    const int grid  = (n_out + NT - 1) / NT;

    hipLaunchKernelGGL(sage_fused3, dim3(grid), dim3(NTHREADS), 0, stream,
                       x, rp, ci, W, lb, bb, y, n_out);
}

// Round 4
// 118.948 us; speedup vs baseline: 5.9344x; 1.2087x over previous
//
#include <hip/hip_runtime.h>
#include <hip/hip_bf16.h>

#define D 128          // D_IN == D_OUT
#define K2 256         // 2*D (concat width)
#define NT 64          // nodes per block
#define NTHREADS 256
#define AGG_LD 264     // bf16 elems per aggB row -> 528B stride (bank-spread frag reads)

typedef __attribute__((ext_vector_type(8))) short bf16x8;  // MFMA A/B frag (4 VGPRs)
typedef __attribute__((ext_vector_type(4))) float f32x4;   // MFMA C/D frag

static __device__ __forceinline__ unsigned short f2bf(float f) {
    __hip_bfloat16 h = __float2bfloat16(f);   // RNE
    return *reinterpret_cast<unsigned short*>(&h);
}

// ---------------- Kernel A: x_feat fp32 -> bf16 table in d_ws ----------------
__global__ __launch_bounds__(256)
void convert_bf16(const float* __restrict__ x, unsigned int* __restrict__ xb2,
                  long n4)   // n4 = total elements / 4
{
    long i = (long)blockIdx.x * blockDim.x + threadIdx.x;
    const long stride = (long)gridDim.x * blockDim.x;
    for (; i < n4; i += stride) {
        const float4 v = reinterpret_cast<const float4*>(x)[i];
        const unsigned int lo = (unsigned int)f2bf(v.x) | ((unsigned int)f2bf(v.y) << 16);
        const unsigned int hi = (unsigned int)f2bf(v.z) | ((unsigned int)f2bf(v.w) << 16);
        reinterpret_cast<uint2*>(xb2)[i] = make_uint2(lo, hi);
    }
}

// ------------- Kernel B: bf16 gather + mean + concat + MFMA GEMM -------------
__global__ __launch_bounds__(NTHREADS, 3)
void sage_fused_bf16(const unsigned short* __restrict__ xb,
                     const int* __restrict__ rp,
                     const int* __restrict__ ci,
                     const float* __restrict__ W,
                     const float* __restrict__ lb,
                     const float* __restrict__ bb,
                     float* __restrict__ y,
                     int n_out)
{
    __shared__ unsigned short aggB[NT][AGG_LD];  // bf16 [self(128) | mean(128)]
    __shared__ unsigned short wtT[D][32];        // bf16 wtT[o][kk] = W[o][k0+kk]
    __shared__ int rpls[NT + 1];
    __shared__ int cils[NT * 16];

    const int tid   = threadIdx.x;
    const int wave  = tid >> 6;
    const int lane  = tid & 63;
    const int node0 = blockIdx.x * NT;
    const int nt_act = min(NT, n_out - node0);

    if (tid <= nt_act) rpls[tid] = rp[node0 + tid];
    __syncthreads();
    const int e_base = rpls[0];
    const int e_cnt  = rpls[nt_act] - e_base;
    const bool fits  = (e_cnt <= NT * 16);
    if (fits) {
        for (int i = tid; i < e_cnt; i += NTHREADS) cils[i] = ci[e_base + i];
    }
    __syncthreads();

    // ---- Phase 1: gather. 2 nodes per iter -> 32 independent 4B/lane loads ----
    for (int t = 0; t < 16; t += 2) {
        const int nn0 = wave * 16 + t;
        if (nn0 >= nt_act) break;
        const int nn1 = nn0 + 1;
        const bool has1 = (nn1 < nt_act);

        const int s0 = rpls[nn0] - e_base;
        const int d0 = rpls[nn0 + 1] - e_base - s0;
        const int s1 = has1 ? rpls[nn1] - e_base : 0;
        const int d1 = has1 ? rpls[nn1 + 1] - e_base - s1 : 0;

        // self rows (bf16 pair per lane)
        const unsigned int self0 = *reinterpret_cast<const unsigned int*>(
            &xb[(size_t)(node0 + nn0) * D + lane * 2]);
        unsigned int self1 = 0;
        if (has1) self1 = *reinterpret_cast<const unsigned int*>(
            &xb[(size_t)(node0 + nn1) * D + lane * 2]);

        float a0x = 0.f, a0y = 0.f, a1x = 0.f, a1y = 0.f;
        if (fits && d0 == 16 && d1 == 16) {
            int idx0[16], idx1[16];
            #pragma unroll
            for (int u = 0; u < 16; ++u) { idx0[u] = cils[s0 + u]; idx1[u] = cils[s1 + u]; }
            #pragma unroll
            for (int u = 0; u < 16; ++u) {
                const unsigned int v0 = *reinterpret_cast<const unsigned int*>(
                    &xb[(size_t)idx0[u] * D + lane * 2]);
                const unsigned int v1 = *reinterpret_cast<const unsigned int*>(
                    &xb[(size_t)idx1[u] * D + lane * 2]);
                a0x += __uint_as_float(v0 << 16);
                a0y += __uint_as_float(v0 & 0xffff0000u);
                a1x += __uint_as_float(v1 << 16);
                a1y += __uint_as_float(v1 & 0xffff0000u);
            }
        } else {
            for (int u = 0; u < d0; ++u) {
                const int c = fits ? cils[s0 + u] : ci[e_base + s0 + u];
                const unsigned int v = *reinterpret_cast<const unsigned int*>(
                    &xb[(size_t)c * D + lane * 2]);
                a0x += __uint_as_float(v << 16);
                a0y += __uint_as_float(v & 0xffff0000u);
            }
            for (int u = 0; u < d1; ++u) {
                const int c = fits ? cils[s1 + u] : ci[e_base + s1 + u];
                const unsigned int v = *reinterpret_cast<const unsigned int*>(
                    &xb[(size_t)c * D + lane * 2]);
                a1x += __uint_as_float(v << 16);
                a1y += __uint_as_float(v & 0xffff0000u);
            }
        }

        const float inv0 = 1.0f / (float)max(d0, 1);
        *reinterpret_cast<unsigned int*>(&aggB[nn0][lane * 2]) = self0;
        *reinterpret_cast<unsigned int*>(&aggB[nn0][D + lane * 2]) =
            (unsigned int)f2bf(a0x * inv0) | ((unsigned int)f2bf(a0y * inv0) << 16);
        if (has1) {
            const float inv1 = 1.0f / (float)max(d1, 1);
            *reinterpret_cast<unsigned int*>(&aggB[nn1][lane * 2]) = self1;
            *reinterpret_cast<unsigned int*>(&aggB[nn1][D + lane * 2]) =
                (unsigned int)f2bf(a1x * inv1) | ((unsigned int)f2bf(a1y * inv1) << 16);
        }
    }
    // (first __syncthreads in GEMM loop publishes aggB)

    // ---- Phase 2: MFMA GEMM. Per wave: M=16 nodes x N=128 outs, K=256 ----
    const int n15 = lane & 15;
    const int g   = lane >> 4;

    f32x4 acc[8];
    #pragma unroll
    for (int f = 0; f < 8; ++f) acc[f] = (f32x4){0.f, 0.f, 0.f, 0.f};

    for (int k0 = 0; k0 < K2; k0 += 32) {
        #pragma unroll
        for (int j = 0; j < 4; ++j) {
            const int idx = j * 256 + tid;       // 1024 float4s per chunk
            const int o   = idx >> 3;            // 0..127
            const int c   = idx & 7;             // 0..7
            const float4 w = *reinterpret_cast<const float4*>(
                &W[(size_t)o * K2 + k0 + c * 4]);
            const unsigned int lo = (unsigned int)f2bf(w.x) | ((unsigned int)f2bf(w.y) << 16);
            const unsigned int hi = (unsigned int)f2bf(w.z) | ((unsigned int)f2bf(w.w) << 16);
            *reinterpret_cast<uint2*>(&wtT[o][c * 4]) = make_uint2(lo, hi);
        }
        __syncthreads();

        const bf16x8 a = *reinterpret_cast<const bf16x8*>(
            &aggB[wave * 16 + n15][k0 + g * 8]);
        #pragma unroll
        for (int f = 0; f < 8; ++f) {
            const bf16x8 b = *reinterpret_cast<const bf16x8*>(&wtT[f * 16 + n15][g * 8]);
            acc[f] = __builtin_amdgcn_mfma_f32_16x16x32_bf16(a, b, acc[f], 0, 0, 0);
        }
        __syncthreads();
    }

    // ---- Epilogue: D layout col = lane&15, row = (lane>>4)*4 + reg ----
    const int mbase = node0 + wave * 16 + g * 4;
    #pragma unroll
    for (int f = 0; f < 8; ++f) {
        const int col  = f * 16 + n15;
        const float bs = lb[col] + bb[col];
        #pragma unroll
        for (int r = 0; r < 4; ++r) {
            const int row = mbase + r;
            if (row < n_out)
                y[(size_t)row * D + col] = acc[f][r] + bs;
        }
    }
}

// --------- Fallback (R3 kernel, fp32 gather) if ws too small for xb ---------
__global__ __launch_bounds__(NTHREADS, 3)
void sage_fused3(const float* __restrict__ x,
                 const int* __restrict__ rp,
                 const int* __restrict__ ci,
                 const float* __restrict__ W,
                 const float* __restrict__ lb,
                 const float* __restrict__ bb,
                 float* __restrict__ y,
                 int n_out)
{
    __shared__ unsigned short aggB[NT][AGG_LD];
    __shared__ unsigned short wtT[D][32];
    __shared__ int rpls[NT + 1];
    __shared__ int cils[NT * 16];

    const int tid   = threadIdx.x;
    const int wave  = tid >> 6;
    const int lane  = tid & 63;
    const int node0 = blockIdx.x * NT;
    const int nt_act = min(NT, n_out - node0);

    if (tid <= nt_act) rpls[tid] = rp[node0 + tid];
    __syncthreads();
    const int e_base = rpls[0];
    const int e_cnt  = rpls[nt_act] - e_base;
    const bool fits  = (e_cnt <= NT * 16);
    if (fits) {
        for (int i = tid; i < e_cnt; i += NTHREADS) cils[i] = ci[e_base + i];
    }
    __syncthreads();

    for (int t = 0; t < 16; ++t) {
        const int nn = wave * 16 + t;
        if (nn >= nt_act) break;
        const int node = node0 + nn;
        const float2 self =
            *reinterpret_cast<const float2*>(&x[(size_t)node * D + lane * 2]);
        const int s  = rpls[nn] - e_base;
        const int dg = rpls[nn + 1] - e_base - s;
        float ax = 0.f, ay = 0.f;
        if (fits && dg == 16) {
            int idx[16];
            #pragma unroll
            for (int u = 0; u < 16; ++u) idx[u] = cils[s + u];
            #pragma unroll
            for (int u = 0; u < 16; ++u) {
                const float2 v = *reinterpret_cast<const float2*>(
                    &x[(size_t)idx[u] * D + lane * 2]);
                ax += v.x; ay += v.y;
            }
        } else {
            for (int u = 0; u < dg; ++u) {
                const int c = fits ? cils[s + u] : ci[e_base + s + u];
                const float2 v = *reinterpret_cast<const float2*>(
                    &x[(size_t)c * D + lane * 2]);
                ax += v.x; ay += v.y;
            }
        }
        const float inv = 1.0f / (float)max(dg, 1);
        *reinterpret_cast<unsigned int*>(&aggB[nn][lane * 2]) =
            (unsigned int)f2bf(self.x) | ((unsigned int)f2bf(self.y) << 16);
        *reinterpret_cast<unsigned int*>(&aggB[nn][D + lane * 2]) =
            (unsigned int)f2bf(ax * inv) | ((unsigned int)f2bf(ay * inv) << 16);
    }

    const int n15 = lane & 15;
    const int g   = lane >> 4;
    f32x4 acc[8];
    #pragma unroll
    for (int f = 0; f < 8; ++f) acc[f] = (f32x4){0.f, 0.f, 0.f, 0.f};

    for (int k0 = 0; k0 < K2; k0 += 32) {
        #pragma unroll
        for (int j = 0; j < 4; ++j) {
            const int idx = j * 256 + tid;
            const int o   = idx >> 3;
            const int c   = idx & 7;
            const float4 w = *reinterpret_cast<const float4*>(
                &W[(size_t)o * K2 + k0 + c * 4]);
            const unsigned int lo = (unsigned int)f2bf(w.x) | ((unsigned int)f2bf(w.y) << 16);
            const unsigned int hi = (unsigned int)f2bf(w.z) | ((unsigned int)f2bf(w.w) << 16);
            *reinterpret_cast<uint2*>(&wtT[o][c * 4]) = make_uint2(lo, hi);
        }
        __syncthreads();
        const bf16x8 a = *reinterpret_cast<const bf16x8*>(
            &aggB[wave * 16 + n15][k0 + g * 8]);
        #pragma unroll
        for (int f = 0; f < 8; ++f) {
            const bf16x8 b = *reinterpret_cast<const bf16x8*>(&wtT[f * 16 + n15][g * 8]);
            acc[f] = __builtin_amdgcn_mfma_f32_16x16x32_bf16(a, b, acc[f], 0, 0, 0);
        }
        __syncthreads();
    }

    const int mbase = node0 + wave * 16 + g * 4;
    #pragma unroll
    for (int f = 0; f < 8; ++f) {
        const int col  = f * 16 + n15;
        const float bs = lb[col] + bb[col];
        #pragma unroll
        for (int r = 0; r < 4; ++r) {
            const int row = mbase + r;
            if (row < n_out)
                y[(size_t)row * D + col] = acc[f][r] + bs;
        }
    }
}

extern "C" void kernel_launch(void* const* d_in, const int* in_sizes, int n_in,
                              void* d_out, int out_size, void* d_ws, size_t ws_size,
                              hipStream_t stream)
{
    const float* x  = (const float*)d_in[0];
    const int*   rp = (const int*)d_in[1];
    const int*   ci = (const int*)d_in[2];
    // d_in[3] = sample_count (scalar) — degree comes from row_ptr
    const float* W  = (const float*)d_in[4];
    const float* lb = (const float*)d_in[5];
    const float* bb = (const float*)d_in[6];
    float* y = (float*)d_out;

    const int n_out = in_sizes[1] - 1;
    const int grid  = (n_out + NT - 1) / NT;

    const size_t n_x_elems = (size_t)in_sizes[0];
    const size_t need = n_x_elems * sizeof(unsigned short);

    if (ws_size >= need) {
        unsigned short* xb = (unsigned short*)d_ws;
        const long n4 = (long)(n_x_elems >> 2);
        hipLaunchKernelGGL(convert_bf16, dim3(2048), dim3(256), 0, stream,
                           x, (unsigned int*)d_ws, n4);
        hipLaunchKernelGGL(sage_fused_bf16, dim3(grid), dim3(NTHREADS), 0, stream,
                           xb, rp, ci, W, lb, bb, y, n_out);
    } else {
        hipLaunchKernelGGL(sage_fused3, dim3(grid), dim3(NTHREADS), 0, stream,
                           x, rp, ci, W, lb, bb, y, n_out);
    }
}